// Round 11
// baseline (257.599 us; speedup 1.0000x reference)
//
#include <hip/hip_runtime.h>
#include <math.h>

namespace {

constexpr int kC  = 200;   // channels
constexpr int kD  = 800;   // 4*C
constexpr int kS  = 25;    // seq
constexpr int kH  = 32;    // hidden
constexpr int kNC = 16;    // classes
constexpr int kR  = 8;     // rows per block (each of 4 waves owns 2 rows)
constexpr int kRW = 800;   // LDS row stride in words (XOR swizzle for banks)

typedef float vfloat4 __attribute__((ext_vector_type(4)));  // native clang vec

// word offset of chunk m (4 floats) within a row: XOR-swizzle bank spreading.
__device__ __forceinline__ int woff(int m) { return (m << 2) ^ ((m & 0x38) >> 1); }

__device__ __forceinline__ float4 ld4(const float* p) { return *(const float4*)p; }
__device__ __forceinline__ float4 ld4nt(const float* p) {
    vfloat4 v = __builtin_nontemporal_load((const vfloat4*)p);
    return make_float4(v.x, v.y, v.z, v.w);
}
__device__ __forceinline__ void   st4(float* p, float4 v) { *(float4*)p = v; }
__device__ __forceinline__ float  hsum4(float4 v) { return (v.x + v.y) + (v.z + v.w); }

__device__ __forceinline__ float4 f4fma(float s, float4 w, float4 a) {
    a.x = fmaf(s, w.x, a.x); a.y = fmaf(s, w.y, a.y);
    a.z = fmaf(s, w.z, a.z); a.w = fmaf(s, w.w, a.w);
    return a;
}
__device__ __forceinline__ float4 f4add(float4 a, float4 b) {
    return make_float4(a.x + b.x, a.y + b.y, a.z + b.z, a.w + b.w);
}

// Intra-wave LDS fence: wave-local RAW through LDS only needs lgkmcnt(0).
__device__ __forceinline__ void wfence() {
    asm volatile("s_waitcnt lgkmcnt(0)" ::: "memory");
}

// ---------------- phase 1: x -> h workspace (pure streaming) ----------------
__global__ __launch_bounds__(256)
void featurize_kernel(const float* __restrict__ x, float* __restrict__ hws, int Btot)
{
    const int gid = blockIdx.x * 256 + threadIdx.x;
    if (gid >= Btot * 50) return;
    const int row = gid / 50;
    const int cq  = gid - row * 50;

    const float* xp = x + (size_t)row * (kS * kC) + cq * 4;
    float4 v = ld4nt(xp);
    float4 mn = v, mx = v, sm = v;
    #pragma unroll
    for (int s = 1; s < kS - 1; ++s) {
        float4 u = ld4nt(xp + s * kC);
        mn.x = fminf(mn.x, u.x); mx.x = fmaxf(mx.x, u.x); sm.x += u.x;
        mn.y = fminf(mn.y, u.y); mx.y = fmaxf(mx.y, u.y); sm.y += u.y;
        mn.z = fminf(mn.z, u.z); mx.z = fmaxf(mx.z, u.z); sm.z += u.z;
        mn.w = fminf(mn.w, u.w); mx.w = fmaxf(mx.w, u.w); sm.w += u.w;
    }
    float4 last = ld4nt(xp + (kS - 1) * kC);
    const float i24 = 1.0f / 24.0f;
    float* hp = hws + (size_t)row * kD + 16 * cq;   // plain row-major h
    st4(hp + 0,  make_float4(mn.x, sm.x * i24, last.x, mx.x));
    st4(hp + 4,  make_float4(mn.y, sm.y * i24, last.y, mx.y));
    st4(hp + 8,  make_float4(mn.z, sm.z * i24, last.z, mx.z));
    st4(hp + 12, make_float4(mn.w, sm.w * i24, last.w, mx.w));
}

// LayerNorm over register-resident row (4 chunks/lane), writes y into zb row.
__device__ __forceinline__ void ln_reg(float4 c0, float4 c1, float4 c2, float4 c3,
                                       bool tail, int j,
                                       const float* __restrict__ g,
                                       const float* __restrict__ bb,
                                       float* yrow)
{
    float sm = hsum4(c0) + hsum4(c1) + hsum4(c2) + (tail ? hsum4(c3) : 0.f);
    #pragma unroll
    for (int mk = 32; mk >= 1; mk >>= 1) sm += __shfl_xor(sm, mk, 64);
    const float mean = sm * (1.0f / 800.0f);

    float ssq = 0.f;
    { float a=c0.x-mean,b=c0.y-mean,c=c0.z-mean,d=c0.w-mean; ssq += a*a+b*b+c*c+d*d; }
    { float a=c1.x-mean,b=c1.y-mean,c=c1.z-mean,d=c1.w-mean; ssq += a*a+b*b+c*c+d*d; }
    { float a=c2.x-mean,b=c2.y-mean,c=c2.z-mean,d=c2.w-mean; ssq += a*a+b*b+c*c+d*d; }
    if (tail) { float a=c3.x-mean,b=c3.y-mean,c=c3.z-mean,d=c3.w-mean; ssq += a*a+b*b+c*c+d*d; }
    #pragma unroll
    for (int mk = 32; mk >= 1; mk >>= 1) ssq += __shfl_xor(ssq, mk, 64);
    const float rstd = rsqrtf(ssq * (1.0f / 800.0f) + 1e-5f);

    auto stc = [&](int m, float4 v) {
        float4 g4 = ld4(&g[4 * m]);
        float4 b4 = ld4(&bb[4 * m]);
        float4 y;
        y.x = (v.x - mean) * rstd * g4.x + b4.x;
        y.y = (v.y - mean) * rstd * g4.y + b4.y;
        y.z = (v.z - mean) * rstd * g4.z + b4.z;
        y.w = (v.w - mean) * rstd * g4.w + b4.w;
        st4(&yrow[woff(m)], y);
    };
    stc(j, c0); stc(j + 64, c1); stc(j + 128, c2);
    if (tail) stc(192 + j, c3);
}

// sppcf contribution for chunk m, read y from LDS row, return updated h chunk.
__device__ __forceinline__ float4 sppcf_one(const float* yrow, int m, float4 h4)
{
    const int kk = (m <= 196) ? m : m - 4;          // f2 tail -> p16[m-4]
    float4 q0 = ld4(&yrow[woff(kk)]);
    float4 q1 = ld4(&yrow[woff(kk + 1)]);
    float4 q2 = ld4(&yrow[woff(kk + 2)]);
    float4 q3 = ld4(&yrow[woff(kk + 3)]);
    float4 y4 = (m <= 196) ? q0 : ld4(&yrow[woff(m)]);
    const float s16 = hsum4(q0) + hsum4(q1) + hsum4(q2) + hsum4(q3);
    h4.x += (y4.x + y4.y) * 0.5f;
    h4.y += (y4.x + y4.y + y4.z + y4.w) * 0.25f;
    h4.z += (y4.z + y4.w) * 0.5f;
    h4.w += s16 * (1.0f / 16.0f);
    return h4;
}

// ---------------- phase 2: transformer layers + head ----------------
// h is REGISTER-RESIDENT: each wave owns rows w and w+4 (4 float4 chunks/lane/row).
// LDS: only zb (y/z/partials/mm2-out/pooled) + vb (gelu). 26.6 KB/block.
template<bool FROMWS>
__global__ __launch_bounds__(256)
void essp_main(const float* __restrict__ src,
               const float* __restrict__ lnA_g, const float* __restrict__ lnA_b,
               const float* __restrict__ lnB_g, const float* __restrict__ lnB_b,
               const float* __restrict__ w1, const float* __restrict__ b1,
               const float* __restrict__ w2, const float* __restrict__ b2,
               const float* __restrict__ fc_w, const float* __restrict__ fc_b,
               float* __restrict__ out, int Btot)
{
    __shared__ float zb[kR * kRW];   // y/z; mm1 partials; mm2 out; pooled
    __shared__ float vb[kR * kH];    // gelu outputs

    const int t    = threadIdx.x;
    const int w    = t >> 6;         // wave id; owns rows w and w+4
    const int j    = t & 63;         // lane
    const int b0   = blockIdx.x * kR;
    const bool tail = (j < 8);

    float4 h0[4], h1[4];             // register h: [chunk] for row w, row w+4

    // ---- load/compute h into registers ----
    {
        const int r0 = min(b0 + w,     Btot - 1);
        const int r1 = min(b0 + w + 4, Btot - 1);
        if constexpr (FROMWS) {
            const float* hg0 = src + (size_t)r0 * kD;
            const float* hg1 = src + (size_t)r1 * kD;
            h0[0] = ld4(&hg0[4 * j]);
            h0[1] = ld4(&hg0[4 * (j + 64)]);
            h0[2] = ld4(&hg0[4 * (j + 128)]);
            h0[3] = tail ? ld4(&hg0[4 * (192 + j)]) : make_float4(0.f,0.f,0.f,0.f);
            h1[0] = ld4(&hg1[4 * j]);
            h1[1] = ld4(&hg1[4 * (j + 64)]);
            h1[2] = ld4(&hg1[4 * (j + 128)]);
            h1[3] = tail ? ld4(&hg1[4 * (192 + j)]) : make_float4(0.f,0.f,0.f,0.f);
        } else {
            // fused featurize into zb scratch, then pick up into regs (wave-local)
            #pragma unroll
            for (int rr = 0; rr < 2; ++rr) {
                const int lr  = w + 4 * rr;
                const int row = (rr == 0) ? r0 : r1;
                if (j < 50) {
                    const float* xp = src + (size_t)row * (kS * kC) + j * 4;
                    float4 v = ld4nt(xp);
                    float4 mn = v, mx = v, sm = v;
                    #pragma unroll
                    for (int s = 1; s < kS - 1; ++s) {
                        float4 u = ld4nt(xp + s * kC);
                        mn.x = fminf(mn.x, u.x); mx.x = fmaxf(mx.x, u.x); sm.x += u.x;
                        mn.y = fminf(mn.y, u.y); mx.y = fmaxf(mx.y, u.y); sm.y += u.y;
                        mn.z = fminf(mn.z, u.z); mx.z = fmaxf(mx.z, u.z); sm.z += u.z;
                        mn.w = fminf(mn.w, u.w); mx.w = fmaxf(mx.w, u.w); sm.w += u.w;
                    }
                    float4 last = ld4nt(xp + (kS - 1) * kC);
                    const float i24 = 1.0f / 24.0f;
                    float* hr = &zb[lr * kRW];
                    st4(&hr[woff(4 * j + 0)], make_float4(mn.x, sm.x*i24, last.x, mx.x));
                    st4(&hr[woff(4 * j + 1)], make_float4(mn.y, sm.y*i24, last.y, mx.y));
                    st4(&hr[woff(4 * j + 2)], make_float4(mn.z, sm.z*i24, last.z, mx.z));
                    st4(&hr[woff(4 * j + 3)], make_float4(mn.w, sm.w*i24, last.w, mx.w));
                }
            }
            wfence();
            const float* z0 = &zb[w * kRW];
            const float* z1 = &zb[(w + 4) * kRW];
            h0[0] = ld4(&z0[woff(j)]);
            h0[1] = ld4(&z0[woff(j + 64)]);
            h0[2] = ld4(&z0[woff(j + 128)]);
            h0[3] = tail ? ld4(&z0[woff(192 + j)]) : make_float4(0.f,0.f,0.f,0.f);
            h1[0] = ld4(&z1[woff(j)]);
            h1[1] = ld4(&z1[woff(j + 64)]);
            h1[2] = ld4(&z1[woff(j + 128)]);
            h1[3] = tail ? ld4(&z1[woff(192 + j)]) : make_float4(0.f,0.f,0.f,0.f);
            wfence();
        }
    }

    float* yz0 = &zb[w * kRW];
    float* yz1 = &zb[(w + 4) * kRW];

    for (int layer = 0; layer < 2; ++layer) {
        const float* gA  = lnA_g + layer * kD;
        const float* bAv = lnA_b + layer * kD;
        const float* gB  = lnB_g + layer * kD;
        const float* bBv = lnB_b + layer * kD;
        const float* w1p = w1 + layer * kD * kH;
        const float* b1p = b1 + layer * kH;
        const float* w2p = w2 + layer * kH * kD;
        const float* b2p = b2 + layer * kD;

        // ---- LN_A (regs -> y in zb), wave-local ----
        ln_reg(h0[0], h0[1], h0[2], h0[3], tail, j, gA, bAv, yz0);
        ln_reg(h1[0], h1[1], h1[2], h1[3], tail, j, gA, bAv, yz1);
        wfence();
        // ---- h += sppcf(y), updates regs ----
        h0[0] = sppcf_one(yz0, j, h0[0]);
        h0[1] = sppcf_one(yz0, j + 64, h0[1]);
        h0[2] = sppcf_one(yz0, j + 128, h0[2]);
        if (tail) h0[3] = sppcf_one(yz0, 192 + j, h0[3]);
        h1[0] = sppcf_one(yz1, j, h1[0]);
        h1[1] = sppcf_one(yz1, j + 64, h1[1]);
        h1[2] = sppcf_one(yz1, j + 128, h1[2]);
        if (tail) h1[3] = sppcf_one(yz1, 192 + j, h1[3]);
        wfence();
        // ---- LN_B (regs -> z in zb) ----
        ln_reg(h0[0], h0[1], h0[2], h0[3], tail, j, gB, bBv, yz0);
        ln_reg(h1[0], h1[1], h1[2], h1[3], tail, j, gB, bBv, yz1);
        __syncthreads();                       // mm1 reads all rows' z

        // ---- mm1: u = z @ w1, 8-row register amortization ----
        float4 acc[kR];
        const int dg = t >> 3, cg = t & 7;
        #pragma unroll
        for (int r = 0; r < kR; ++r) acc[r] = make_float4(0.f, 0.f, 0.f, 0.f);
        if (t < 200) {
            #pragma unroll
            for (int cc = 0; cc < 8; ++cc) {
                const int m = dg * 8 + cc, d0 = 4 * m;
                float4 wr0 = ld4(&w1p[(d0 + 0) * kH + 4 * cg]);
                float4 wr1 = ld4(&w1p[(d0 + 1) * kH + 4 * cg]);
                float4 wr2 = ld4(&w1p[(d0 + 2) * kH + 4 * cg]);
                float4 wr3 = ld4(&w1p[(d0 + 3) * kH + 4 * cg]);
                const int wo = woff(m);
                #pragma unroll
                for (int r = 0; r < kR; ++r) {
                    float4 z = ld4(&zb[r * kRW + wo]);
                    acc[r] = f4fma(z.x, wr0, acc[r]);
                    acc[r] = f4fma(z.y, wr1, acc[r]);
                    acc[r] = f4fma(z.z, wr2, acc[r]);
                    acc[r] = f4fma(z.w, wr3, acc[r]);
                }
            }
        }
        __syncthreads();                       // everyone done reading z
        if (t < 200) {
            // partials into dead zb: word(r,dg,h)=r*800+dg*32+(h^((dg&7)<<2))
            const int pb = dg * 32 + ((4 * cg) ^ ((dg & 7) << 2));
            #pragma unroll
            for (int r = 0; r < kR; ++r) st4(&zb[r * kRW + pb], acc[r]);
        }
        __syncthreads();

        // ---- reduce partials + bias + exact GELU -> vb (all 256 threads) ----
        {
            const int r = t >> 5, h = t & 31;
            float u = b1p[h];
            #pragma unroll
            for (int dq = 0; dq < 25; ++dq)
                u += zb[r * kRW + dq * 32 + (h ^ ((dq & 7) << 2))];
            vb[r * kH + h] = 0.5f * u * (1.0f + erff(u * 0.70710678118654752440f));
        }
        __syncthreads();

        // ---- mm2: z2 = v @ w2 + b2 -> zb (overwrites dead partials) ----
        if (t < 200) {
            float4 a2[kR];
            #pragma unroll
            for (int r = 0; r < kR; ++r) a2[r] = make_float4(0.f, 0.f, 0.f, 0.f);
            #pragma unroll
            for (int hc = 0; hc < 8; ++hc) {
                float4 wq0 = ld4(&w2p[(4*hc + 0) * kD + 4*t]);
                float4 wq1 = ld4(&w2p[(4*hc + 1) * kD + 4*t]);
                float4 wq2 = ld4(&w2p[(4*hc + 2) * kD + 4*t]);
                float4 wq3 = ld4(&w2p[(4*hc + 3) * kD + 4*t]);
                #pragma unroll
                for (int r = 0; r < kR; ++r) {
                    float4 vq = ld4(&vb[r * kH + 4 * hc]);
                    a2[r] = f4fma(vq.x, wq0, a2[r]);
                    a2[r] = f4fma(vq.y, wq1, a2[r]);
                    a2[r] = f4fma(vq.z, wq2, a2[r]);
                    a2[r] = f4fma(vq.w, wq3, a2[r]);
                }
            }
            const float4 bq = ld4(&b2p[4 * t]);
            const int wo = woff(t);
            #pragma unroll
            for (int r = 0; r < kR; ++r)
                st4(&zb[r * kRW + wo], f4add(a2[r], bq));
        }
        __syncthreads();                        // mm2 outputs visible

        // ---- h(regs) += z2 (each wave consumes its 2 rows) ----
        h0[0] = f4add(h0[0], ld4(&yz0[woff(j)]));
        h0[1] = f4add(h0[1], ld4(&yz0[woff(j + 64)]));
        h0[2] = f4add(h0[2], ld4(&yz0[woff(j + 128)]));
        if (tail) h0[3] = f4add(h0[3], ld4(&yz0[woff(192 + j)]));
        h1[0] = f4add(h1[0], ld4(&yz1[woff(j)]));
        h1[1] = f4add(h1[1], ld4(&yz1[woff(j + 64)]));
        h1[2] = f4add(h1[2], ld4(&yz1[woff(j + 128)]));
        if (tail) h1[3] = f4add(h1[3], ld4(&yz1[woff(192 + j)]));
        wfence();
    }

    // ---- pooled = mean4(h) from regs into zb (plain layout, wave-local) ----
    {
        yz0[j]       = hsum4(h0[0]) * 0.25f;
        yz0[j + 64]  = hsum4(h0[1]) * 0.25f;
        yz0[j + 128] = hsum4(h0[2]) * 0.25f;
        if (tail) yz0[192 + j] = hsum4(h0[3]) * 0.25f;
        yz1[j]       = hsum4(h1[0]) * 0.25f;
        yz1[j + 64]  = hsum4(h1[1]) * 0.25f;
        yz1[j + 128] = hsum4(h1[2]) * 0.25f;
        if (tail) yz1[192 + j] = hsum4(h1[3]) * 0.25f;
    }
    wfence();

    // ---- out = pooled @ fc_w + fc_b (wave-local, 2 rows) ----
    #pragma unroll
    for (int rr = 0; rr < 2; ++rr) {
        const int lr  = w + 4 * rr;
        const int row = b0 + lr;
        const int n = j & 15, sg = j >> 4;
        const float* pr = &zb[lr * kRW + sg * 50];
        const float* fw = fc_w + (size_t)(sg * 50) * kNC + n;
        float acc = 0.f;
        #pragma unroll 10
        for (int i = 0; i < 50; ++i) acc += pr[i] * fw[i * kNC];
        acc += __shfl_xor(acc, 16, 64);
        acc += __shfl_xor(acc, 32, 64);
        if (j < kNC && row < Btot)
            out[(size_t)row * kNC + j] = acc + fc_b[j];
    }
}

} // namespace

extern "C" void kernel_launch(void* const* d_in, const int* in_sizes, int n_in,
                              void* d_out, int out_size, void* d_ws, size_t ws_size,
                              hipStream_t stream) {
    const float* x     = (const float*)d_in[0];
    const float* lnA_g = (const float*)d_in[1];
    const float* lnA_b = (const float*)d_in[2];
    const float* lnB_g = (const float*)d_in[3];
    const float* lnB_b = (const float*)d_in[4];
    const float* w1    = (const float*)d_in[5];
    const float* b1    = (const float*)d_in[6];
    const float* w2    = (const float*)d_in[7];
    const float* b2    = (const float*)d_in[8];
    const float* fc_w  = (const float*)d_in[9];
    const float* fc_b  = (const float*)d_in[10];
    float* out = (float*)d_out;

    const int Btot   = in_sizes[0] / (kS * kC);
    const int blocks = (Btot + kR - 1) / kR;
    const size_t hbytes = (size_t)Btot * kD * sizeof(float);

    if (ws_size >= hbytes) {
        float* hws = (float*)d_ws;
        const int fblocks = (Btot * 50 + 255) / 256;
        hipLaunchKernelGGL(featurize_kernel, dim3(fblocks), dim3(256), 0, stream,
                           x, hws, Btot);
        hipLaunchKernelGGL((essp_main<true>), dim3(blocks), dim3(256), 0, stream,
                           hws, lnA_g, lnA_b, lnB_g, lnB_b, w1, b1, w2, b2,
                           fc_w, fc_b, out, Btot);
    } else {
        hipLaunchKernelGGL((essp_main<false>), dim3(blocks), dim3(256), 0, stream,
                           x, lnA_g, lnA_b, lnB_g, lnB_b, w1, b1, w2, b2,
                           fc_w, fc_b, out, Btot);
    }
}